// Round 3
// baseline (3423.010 us; speedup 1.0000x reference)
//
#include <hip/hip_runtime.h>
#include <math.h>

// ---- problem constants ----
#define BB 64
#define SS 512
#define II 1024
#define HH 1024

typedef _Float16 half8  __attribute__((ext_vector_type(8)));
typedef _Float16 half4_t __attribute__((ext_vector_type(4)));
typedef float    float4_t __attribute__((ext_vector_type(4)));

// ---- workspace layout (bytes) ----
#define XH_OFF   0u            // fp16 x, (S,B,I) layout: 67108864 B
#define WIH_OFF  67108864u     // fp16 W_ih [H][I]: 2097152 B
#define WHH_OFF  69206016u     // fp16 W_hh [H][H]: 2097152 B
#define HBUF_OFF 71303168u     // fp16 h double buffer [2][64][1024]: 262144 B
#define FLG_OFF  71565312u     // 128 per-(WG,wave) flags, 32-B stride (4 KB)

__device__ __forceinline__ void load_lds16(const void* g, void* l) {
  __builtin_amdgcn_global_load_lds(
      (const __attribute__((address_space(1))) void*)g,
      (__attribute__((address_space(3))) void*)l, 16, 0, 0);
}

// ============================================================
// Kernel 0: convert x -> fp16 time-major, weights -> fp16, zero flags
// ============================================================
__global__ __launch_bounds__(256) void convert_kernel(
    const float* __restrict__ x, const float* __restrict__ Wih,
    const float* __restrict__ Whh, _Float16* __restrict__ xh,
    _Float16* __restrict__ Wihh, _Float16* __restrict__ Whhh,
    unsigned* __restrict__ flg) {
  long tid = (long)blockIdx.x * blockDim.x + threadIdx.x;
  if (tid < 1024) flg[tid] = 0;
  if (tid < 8388608L) {  // x: 33554432 floats = 8388608 float4
    long f = tid;
    int i4 = (int)(f & 255);          // float4 index within I row
    int s  = (int)((f >> 8) & 511);
    int b  = (int)(f >> 17);
    float4_t v = ((const float4_t*)x)[f];
    half4_t h;
    h[0] = (_Float16)v[0]; h[1] = (_Float16)v[1];
    h[2] = (_Float16)v[2]; h[3] = (_Float16)v[3];
    long dst = ((long)(s * 64 + b) * 1024 + i4 * 4) >> 2;  // half4 units
    ((half4_t*)xh)[dst] = h;
  } else if (tid < 8388608L + 262144L) {
    long f = tid - 8388608L;
    float4_t v = ((const float4_t*)Wih)[f];
    half4_t h;
    h[0] = (_Float16)v[0]; h[1] = (_Float16)v[1];
    h[2] = (_Float16)v[2]; h[3] = (_Float16)v[3];
    ((half4_t*)Wihh)[f] = h;
  } else if (tid < 8388608L + 524288L) {
    long f = tid - 8388608L - 262144L;
    float4_t v = ((const float4_t*)Whh)[f];
    half4_t h;
    h[0] = (_Float16)v[0]; h[1] = (_Float16)v[1];
    h[2] = (_Float16)v[2]; h[3] = (_Float16)v[3];
    ((half4_t*)Whhh)[f] = h;
  }
}

// ============================================================
// Kernel 1: xi = x_h @ W_ih^T + b_ih  (fp16 MFMA, fp32 out -> d_out rows s*B+b)
// ============================================================
__global__ __launch_bounds__(256) void gemm_xi(
    const _Float16* __restrict__ Ap, const _Float16* __restrict__ Bp,
    const float* __restrict__ bias, float* __restrict__ out) {
  __shared__ _Float16 Al[128 * 32];
  __shared__ _Float16 Bl[128 * 32];
  int bid = blockIdx.x;
  int nT = bid & 7, mT = bid >> 3;
  int tid = threadIdx.x;
  int lane = tid & 63, wv = tid >> 6;
  int wm = wv & 1, wn = wv >> 1;
  int nl = lane & 15, quad = lane >> 4;
  long mBase = (long)mT * 128;
  long nBase = (long)nT * 128;
  float4_t acc[4][4] = {};

  for (int k0 = 0; k0 < 1024; k0 += 32) {
    __syncthreads();
#pragma unroll
    for (int c2 = 0; c2 < 2; ++c2) {
      int c = wv * 2 + c2;
      int flat = c * 64 + lane;
      int row = flat >> 2;
      int off = (flat & 3) * 8;
      load_lds16(Ap + (mBase + row) * 1024 + k0 + off, &Al[c * 512]);
      load_lds16(Bp + (nBase + row) * 1024 + k0 + off, &Bl[c * 512]);
    }
    __syncthreads();
    half8 af[4], bf[4];
#pragma unroll
    for (int t = 0; t < 4; ++t) {
      af[t] = *(const half8*)&Al[(wm * 64 + t * 16 + nl) * 32 + quad * 8];
      bf[t] = *(const half8*)&Bl[(wn * 64 + t * 16 + nl) * 32 + quad * 8];
    }
#pragma unroll
    for (int tm = 0; tm < 4; ++tm)
#pragma unroll
      for (int tn = 0; tn < 4; ++tn)
        acc[tm][tn] = __builtin_amdgcn_mfma_f32_16x16x32_f16(
            af[tm], bf[tn], acc[tm][tn], 0, 0, 0);
  }
#pragma unroll
  for (int tm = 0; tm < 4; ++tm) {
    long rowg = mBase + wm * 64 + tm * 16 + quad * 4;
#pragma unroll
    for (int tn = 0; tn < 4; ++tn) {
      long colg = nBase + wn * 64 + tn * 16 + nl;
      float bi = bias[colg];
#pragma unroll
      for (int r = 0; r < 4; ++r)
        out[(rowg + r) * 1024 + colg] = acc[tm][tn][r] + bi;
    }
  }
}

// ============================================================
// Kernel 2: persistent recurrence — 32 WGs x 256 thr, k-sliced waves.
// WG `slice` owns output cols [slice*32, +32). Wave wv owns k-slice
// [256*wv, +256) -> its W (B-operand) fragments = 16 half8 = 64 VGPRs,
// loaded ONCE from global. No per-step W LDS streaming at all.
//
// Per step: wave polls only its 8 producer WGs' per-wave flag words,
// loads its 32 KB h k-slice (global_load_dwordx4 sc0 sc1), runs 64
// MFMAs (4 m-tiles x 2 n-tiles x 8 k-steps), then cross-wave k-reduce
// through double-buffered LDS (ONE barrier/step). Epilogue ownership =
// bat-quarter (m-tile == wv): tanh, wave-local LDS transpose, per-wave
// 1 KB contiguous sc1 publish, own vmcnt(0), per-wave flag word.
// Fence-free: all cross-WG data device-scope (sc1) as in Round 2.
// ============================================================
__global__ __launch_bounds__(256, 1) void rnn_rec(
    const _Float16* __restrict__ Whh, const float* __restrict__ bhh,
    float* __restrict__ out, _Float16* __restrict__ hbuf,
    unsigned* __restrict__ flags) {
  __shared__ __align__(16) float red[2][4][4][2][256];  // 64 KB [buf][src][q][n][nl*16+quad*4+r]
  __shared__ __align__(16) _Float16 hstage[4][512];     // 4 KB, wave-local transpose
  const int slice = blockIdx.x;        // 0..31
  const int tid = threadIdx.x;
  const int wv = tid >> 6, lane = tid & 63;
  const int nl = lane & 15, quad = lane >> 4;
  const int colbase = slice * 32;

  // one-time W fragment load: wfrag[n][t] = W rows colbase+n*16+nl,
  // k = wv*256 + t*32 + quad*8 .. +8   (64 VGPRs, resident all steps)
  half8 wfrag[2][8];
#pragma unroll
  for (int n = 0; n < 2; ++n)
#pragma unroll
    for (int t = 0; t < 8; ++t)
      wfrag[n][t] = *(const half8*)(Whh + (long)(colbase + n * 16 + nl) * 1024 +
                                    wv * 256 + t * 32 + quad * 8);

  const int mycol0 = colbase + nl, mycol1 = colbase + 16 + nl;
  const float bi0 = bhh[mycol0], bi1 = bhh[mycol1];
  const int mybat = wv * 16 + quad * 4;   // epilogue bats mybat..mybat+3
  const int ri = nl * 16 + quad * 4;      // red inner index

#pragma unroll 1
  for (int s = 0; s < 512; ++s) {
    // ---- xi prefetch (epilogue bats), in flight during poll/load ----
    float xi0[4], xi1[4];
#pragma unroll
    for (int r = 0; r < 4; ++r) {
      long rowo = ((long)s * 64 + mybat + r) * 1024;
      xi0[r] = out[rowo + mycol0];
      xi1[r] = out[rowo + mycol1];
    }

    float4_t acc[4][2] = {};
    if (s > 0) {
      // poll ONLY this wave's 8 producers x 4 wave-words: word = 32*wv + l
      {
        const unsigned widx = ((unsigned)(wv * 32 + (lane & 31))) << 3;  // 32-B stride
        while (true) {
          unsigned f = __hip_atomic_load(&flags[widx], __ATOMIC_RELAXED,
                                         __HIP_MEMORY_SCOPE_AGENT);
          if (__ballot(f < (unsigned)s) == 0ull) break;
          __builtin_amdgcn_s_sleep(1);
        }
      }
      // h k-slice: 32 x 16B per lane, rows m*16+nl, k-window wv*256
      const _Float16* hb = hbuf + ((s - 1) & 1) * 65536 + wv * 256 + quad * 8;
      float4_t hf[4][8];
      __builtin_amdgcn_sched_barrier(0);
#pragma unroll
      for (int m = 0; m < 4; ++m)
#pragma unroll
        for (int t = 0; t < 8; ++t)
          asm volatile("global_load_dwordx4 %0, %1, off sc0 sc1"
                       : "=v"(hf[m][t])
                       : "v"(hb + ((m * 16 + nl) << 10) + t * 32));
      asm volatile("s_waitcnt vmcnt(0)" ::: "memory");
      __builtin_amdgcn_sched_barrier(0);  // rule 18: pin MFMAs below the wait
#pragma unroll
      for (int t = 0; t < 8; ++t)
#pragma unroll
        for (int m = 0; m < 4; ++m) {
          half8 a = __builtin_bit_cast(half8, hf[m][t]);
          acc[m][0] = __builtin_amdgcn_mfma_f32_16x16x32_f16(
              a, wfrag[0][t], acc[m][0], 0, 0, 0);
          acc[m][1] = __builtin_amdgcn_mfma_f32_16x16x32_f16(
              a, wfrag[1][t], acc[m][1], 0, 0, 0);
        }
    }

    // ---- cross-wave k-reduction (double-buffered, ONE barrier/step) ----
#pragma unroll
    for (int m = 0; m < 4; ++m)
#pragma unroll
      for (int n = 0; n < 2; ++n)
        *(float4_t*)&red[s & 1][wv][m][n][ri] = acc[m][n];
    __syncthreads();
    float4_t fin0, fin1;
    {
      float4_t a0 = *(const float4_t*)&red[s & 1][0][wv][0][ri];
      float4_t b0 = *(const float4_t*)&red[s & 1][1][wv][0][ri];
      float4_t c0 = *(const float4_t*)&red[s & 1][2][wv][0][ri];
      float4_t d0 = *(const float4_t*)&red[s & 1][3][wv][0][ri];
      fin0 = (a0 + b0) + (c0 + d0);
      float4_t a1 = *(const float4_t*)&red[s & 1][0][wv][1][ri];
      float4_t b1 = *(const float4_t*)&red[s & 1][1][wv][1][ri];
      float4_t c1 = *(const float4_t*)&red[s & 1][2][wv][1][ri];
      float4_t d1 = *(const float4_t*)&red[s & 1][3][wv][1][ri];
      fin1 = (a1 + b1) + (c1 + d1);
    }

    // ---- epilogue: h = tanh(xi + acc + bhh), wave-local transpose ----
    float hv0[4], hv1[4];
#pragma unroll
    for (int r = 0; r < 4; ++r) {
      float pre0 = fin0[r] + xi0[r] + bi0;
      float e0 = __expf(2.f * pre0);
      float v0 = 1.f - 2.f / (e0 + 1.f);
      hv0[r] = v0;
      hstage[wv][(quad * 4 + r) * 32 + nl] = (_Float16)v0;
      float pre1 = fin1[r] + xi1[r] + bi1;
      float e1 = __expf(2.f * pre1);
      float v1 = 1.f - 2.f / (e1 + 1.f);
      hv1[r] = v1;
      hstage[wv][(quad * 4 + r) * 32 + 16 + nl] = (_Float16)v1;
    }
    // wave-local read (lgkmcnt-only dependency, no barrier needed):
    // lane l publishes bat 16*wv + (l>>2), col chunk (l&3)*8 (16 B)
    {
      float4_t pv = *(const float4_t*)&hstage[wv][(lane >> 2) * 32 + (lane & 3) * 8];
      _Float16* dst = hbuf + (s & 1) * 65536 +
                      ((wv * 16 + (lane >> 2)) << 10) + colbase + (lane & 3) * 8;
      asm volatile("global_store_dwordx4 %0, %1, off sc0 sc1"
                   :: "v"(dst), "v"(pv) : "memory");
      asm volatile("s_waitcnt vmcnt(0)" ::: "memory");  // this wave's publish acked @MALL
      if (lane == 0)
        __hip_atomic_store(&flags[((unsigned)(slice * 4 + wv)) << 3],
                           (unsigned)(s + 1), __ATOMIC_RELAXED,
                           __HIP_MEMORY_SCOPE_AGENT);
    }

    // ---- out stores off the critical path ----
#pragma unroll
    for (int r = 0; r < 4; ++r) {
      long rowo = ((long)s * 64 + mybat + r) * 1024;
      out[rowo + mycol0] = hv0[r];
      out[rowo + mycol1] = hv1[r];
      if (s == 511) {
        out[33554432L + (mybat + r) * 1024 + mycol0] = hv0[r];
        out[33554432L + (mybat + r) * 1024 + mycol1] = hv1[r];
      }
    }
  }
}

// ============================================================
extern "C" void kernel_launch(void* const* d_in, const int* in_sizes, int n_in,
                              void* d_out, int out_size, void* d_ws,
                              size_t ws_size, hipStream_t stream) {
  const float* x   = (const float*)d_in[0];
  const float* Wih = (const float*)d_in[1];
  const float* bih = (const float*)d_in[2];
  const float* Whh = (const float*)d_in[3];
  const float* bhh = (const float*)d_in[4];
  char* ws = (char*)d_ws;
  _Float16* xh   = (_Float16*)(ws + XH_OFF);
  _Float16* Wihh = (_Float16*)(ws + WIH_OFF);
  _Float16* Whhh = (_Float16*)(ws + WHH_OFF);
  _Float16* hbuf = (_Float16*)(ws + HBUF_OFF);
  unsigned* flg  = (unsigned*)(ws + FLG_OFF);
  float* out = (float*)d_out;

  convert_kernel<<<34816, 256, 0, stream>>>(x, Wih, Whh, xh, Wihh, Whhh, flg);
  gemm_xi<<<2048, 256, 0, stream>>>(xh, Wihh, bih, out);
  rnn_rec<<<32, 256, 0, stream>>>(Whhh, bhh, out, hbuf, flg);
}